// Round 14
// baseline (81.347 us; speedup 1.0000x reference)
//
#include <hip/hip_runtime.h>
#include <hip/hip_bf16.h>

#define NPER 24
#define B_ 32
#define N_ 1024
#define F_ 128
#define H_ 64
#define E_ 16

typedef __attribute__((ext_vector_type(8))) short short8;
typedef __attribute__((ext_vector_type(4))) float f32x4;

#define GLD16(g, l) __builtin_amdgcn_global_load_lds( \
    (const __attribute__((address_space(1))) void*)(g), \
    (__attribute__((address_space(3))) void*)(l), 16, 0, 0)

static __device__ __forceinline__ unsigned short f2bf(float x) {
    union { float f; unsigned u; } v; v.f = x;
    unsigned r = v.u + 0x7fffu + ((v.u >> 16) & 1u);   // RNE
    return (unsigned short)(r >> 16);
}
static __device__ __forceinline__ float bf2f(unsigned short h) {
    union { unsigned u; float f; } v; v.u = ((unsigned)h) << 16; return v.f;
}
static __device__ __forceinline__ unsigned short f2bf_hw(float x) {
    __hip_bfloat16 h = __float2bfloat16(x);
    return *(unsigned short*)&h;
}

// ---------------------------------------------------------------------------
// P1: all prep in one launch.  [unchanged, verified]
// ---------------------------------------------------------------------------
__global__ __launch_bounds__(256) void prep_all(
    const float* __restrict__ src_emb, const float* __restrict__ tgt_emb,
    const float* __restrict__ env_features, const float* __restrict__ env_W,
    const float* __restrict__ env_b,
    const float* __restrict__ adj, const float* __restrict__ W,
    const float* __restrict__ rW,
    unsigned short* __restrict__ src_bf, unsigned short* __restrict__ tgt_bf,
    unsigned short* __restrict__ adj_bf, unsigned short* __restrict__ Wt,
    unsigned short* __restrict__ rWt)
{
    const int bid = blockIdx.x;
    if (bid < 256) {
        const int idx = bid * 256 + threadIdx.x;   // 0..65535
        const int n = idx >> 6, h = idx & 63;
        float e = env_b[h];
#pragma unroll
        for (int k = 0; k < E_; ++k)
            e = fmaf(env_features[n * E_ + k], env_W[k * H_ + h], e);
        e = fmaxf(e, 0.f);
#pragma unroll 4
        for (int p = 0; p < NPER; ++p) {
            const size_t off = (size_t)p * (N_ * H_) + idx;
            src_bf[off] = f2bf(src_emb[off] + e);
            tgt_bf[off] = f2bf(tgt_emb[off] + e);
        }
    } else if (bid < 1280) {
        const size_t i = ((size_t)(bid - 256) * 256 + threadIdx.x) * 4;
        float4 v = *(const float4*)(adj + i);
        ushort4 o;
        o.x = f2bf(v.x); o.y = f2bf(v.y); o.z = f2bf(v.z); o.w = f2bf(v.w);
        *(ushort4*)(adj_bf + i) = o;
    } else {
        const int idx = (bid - 1280) * 256 + threadIdx.x;   // 0..32767
        const int which = idx >> 14, j = idx & 16383;
        const int f = j >> 7, d = j & 127;
        if (which == 0) Wt[f * 128 + d]  = f2bf(W[d * 128 + f]);
        else            rWt[f * 128 + d] = f2bf(rW[d * 128 + f]);
    }
}

// ---------------------------------------------------------------------------
// K5: support^T (swapped GEMM) + residual, both bf16 out, MFMA. [unchanged]
// ---------------------------------------------------------------------------
__global__ __launch_bounds__(256) void gemm2_mfma(
    const float* __restrict__ x,               // [B*N][128] fp32
    const unsigned short* __restrict__ Wt,     // [128f][128d]
    const unsigned short* __restrict__ rWt,    // [128f][128d]
    const float* __restrict__ rb,              // [128]
    unsigned short* __restrict__ supT,         // [B][128f][1024m]
    unsigned short* __restrict__ resid)        // [B*N][128]
{
    const int t = threadIdx.x, w = t >> 6, l = t & 63;
    const int ln = l & 15, kb = l >> 4;
    const int mblk = w >> 1, fhalf = w & 1;
    const int row0 = blockIdx.x * 32;
    const int b   = row0 >> 10;
    const int mg0 = row0 & 1023;

    const float* xrow = x + (size_t)(row0 + mblk * 16 + ln) * 128;
    short8 xa[4];
#pragma unroll
    for (int k = 0; k < 4; ++k) {
        float4 v0 = *(const float4*)(xrow + k * 32 + kb * 8);
        float4 v1 = *(const float4*)(xrow + k * 32 + kb * 8 + 4);
        short8 s;
        s[0] = (short)f2bf(v0.x); s[1] = (short)f2bf(v0.y);
        s[2] = (short)f2bf(v0.z); s[3] = (short)f2bf(v0.w);
        s[4] = (short)f2bf(v1.x); s[5] = (short)f2bf(v1.y);
        s[6] = (short)f2bf(v1.z); s[7] = (short)f2bf(v1.w);
        xa[k] = s;
    }

    f32x4 accS[4], accR[4];
#pragma unroll
    for (int i = 0; i < 4; ++i) { accS[i] = (f32x4){0,0,0,0}; accR[i] = (f32x4){0,0,0,0}; }

#pragma unroll
    for (int k = 0; k < 4; ++k) {
#pragma unroll
        for (int fb = 0; fb < 4; ++fb) {
            int fr = (fhalf * 4 + fb) * 16 + ln;
            short8 wa = *(const short8*)(Wt  + (size_t)fr * 128 + k * 32 + kb * 8);
            short8 wb = *(const short8*)(rWt + (size_t)fr * 128 + k * 32 + kb * 8);
            accS[fb] = __builtin_amdgcn_mfma_f32_16x16x32_bf16(wa, xa[k], accS[fb], 0, 0, 0);
            accR[fb] = __builtin_amdgcn_mfma_f32_16x16x32_bf16(xa[k], wb, accR[fb], 0, 0, 0);
        }
    }

#pragma unroll
    for (int fb = 0; fb < 4; ++fb) {
        int m = mg0 + mblk * 16 + ln;
#pragma unroll
        for (int i = 0; i < 4; ++i) {
            int f = (fhalf * 4 + fb) * 16 + kb * 4 + i;
            supT[((size_t)b * 128 + f) * 1024 + m] = f2bf(accS[fb][i]);
        }
    }
#pragma unroll
    for (int fb = 0; fb < 4; ++fb) {
        int f = (fhalf * 4 + fb) * 16 + ln;
        float rbf = rb[f];
#pragma unroll
        for (int i = 0; i < 4; ++i) {
            size_t row = (size_t)row0 + mblk * 16 + kb * 4 + i;
            resid[row * 128 + f] = f2bf(fmaxf(accR[fb][i] + rbf, 0.f));
        }
    }
}

// ---------------------------------------------------------------------------
// K6: occupancy restructure, CORRECT wave decomposition.
// Block = (b, 32-row n-tile), grid 1024 = 4 blocks/CU (LDS ~29 KB), 4 waves.
// Wave w: ns = w&1 -> n-strip [n0+ns*16,+16); fh = w>>1 -> f-half [fh*64,+64).
// Scores duplicated across the f-pair (cheap); s_a wave-private -> no
// cross-wave handoff barrier. Per 32-m chunk: tgt(4KB)+sup(8KB) staged via
// global_load_lds (dbuf); stage t+1 issued at top of chunk t; ONE bar_vm0
// per chunk (r9-proven). Swizzles both-sides (rule #21): tgt 128B rows
// c^(r&7); sup 64B rows c^((r>>1)&3). No counted vmcnt (T4 null in r11).
// ---------------------------------------------------------------------------
__global__ __launch_bounds__(256, 4) void conv_mfma(
    const unsigned short* __restrict__ src_bf,  // [P][N][64]
    const unsigned short* __restrict__ tgt_bf,  // [P][N][64]
    const unsigned short* __restrict__ adj_bf,  // [N][N]
    const unsigned short* __restrict__ supT,    // [B][128][1024]
    const unsigned short* __restrict__ resid,   // [B*N][128]
    const float* __restrict__ bias,             // [128]
    const int* __restrict__ cyc,                // [B]
    float* __restrict__ out)                    // [B][N][128]
{
    __shared__ unsigned short s_tgt[2][32 * 64] __attribute__((aligned(16)));  // 2x4KB
    __shared__ unsigned short s_sup[2][128 * 32] __attribute__((aligned(16))); // 2x8KB
    __shared__ unsigned short s_a[4][16 * 40] __attribute__((aligned(16)));    // 5KB

    const int i = blockIdx.x;                    // 0..1023
    const int work = (i & 7) * 128 + (i >> 3);   // XCD k: 4 consecutive b's
    const int b  = work >> 5;                    // 0..31
    const int n0 = (work & 31) * 32;             // 0..992

    const int t = threadIdx.x, w = t >> 6, l = t & 63;
    const int ln = l & 15, kb = l >> 4;
    const int ns = w & 1;        // n-strip within the 32-row block
    const int fh = w >> 1;       // f-half
    const int p = ((cyc[b] % NPER) + NPER) % NPER;

    // src fragments for this wave's 16-n strip (score B-operand: col n = ln)
    const unsigned short* srow =
        src_bf + ((size_t)p * N_ + n0 + ns * 16 + ln) * H_;
    short8 sfrag[2];
    sfrag[0] = *(const short8*)(srow + kb * 8);
    sfrag[1] = *(const short8*)(srow + 32 + kb * 8);

    const unsigned short* tgtg = tgt_bf + (size_t)p * N_ * H_;
    const unsigned short* supg = supT + (size_t)b * F_ * N_;
    const unsigned short* adjp = adj_bf + (size_t)(n0 + ns * 16 + ln) * N_;
    unsigned short* saw = &s_a[w][0];

    f32x4 acc[4];    // 16n x 64f per wave
#pragma unroll
    for (int q = 0; q < 4; ++q) acc[q] = (f32x4){0, 0, 0, 0};

    auto stage = [&](int buf, int m0) {
        {   // tgt: 32 m-rows x 8 chunks(16B), src-side swizzle c^(r&7)
            const int r = t >> 3, c = t & 7;
            GLD16(tgtg + (size_t)(m0 + r) * H_ + (c ^ (r & 7)) * 8,
                  &s_tgt[buf][t * 8]);
        }
#pragma unroll
        for (int j = 0; j < 2; ++j) {   // sup: 128 f-rows x 4 chunks, c^((r>>1)&3)
            const int te = j * 256 + t;
            const int r = te >> 2, c = te & 3;
            GLD16(supg + (size_t)r * N_ + m0 + (c ^ ((r >> 1) & 3)) * 8,
                  &s_sup[buf][te * 8]);
        }
    };

    auto loadAdj = [&](int m0, ushort4 (&av)[2]) {
#pragma unroll
        for (int mt = 0; mt < 2; ++mt)
            av[mt] = *(const ushort4*)(adjp + m0 + mt * 16 + kb * 4);
    };

    auto score = [&](int buf, const ushort4 (&av)[2]) {
#pragma unroll
        for (int mt = 0; mt < 2; ++mt) {
            const int trow = mt * 16 + ln;     // m-row within chunk
            short8 tf0 = *(const short8*)(
                &s_tgt[buf][trow * 64 + ((kb) ^ (trow & 7)) * 8]);
            short8 tf1 = *(const short8*)(
                &s_tgt[buf][trow * 64 + ((4 + kb) ^ (trow & 7)) * 8]);
            f32x4 c = (f32x4){0, 0, 0, 0};
            c = __builtin_amdgcn_mfma_f32_16x16x32_bf16(tf0, sfrag[0], c, 0, 0, 0);
            c = __builtin_amdgcn_mfma_f32_16x16x32_bf16(tf1, sfrag[1], c, 0, 0, 0);
            // lane holds score[m = mt*16+kb*4+i][n = ln]  (r9-verified layout)
            const ushort4 a = av[mt];
            uint2 q;
            q.x = (unsigned)f2bf_hw(fmaxf(c[0], 0.f) * bf2f(a.x))
                | ((unsigned)f2bf_hw(fmaxf(c[1], 0.f) * bf2f(a.y)) << 16);
            q.y = (unsigned)f2bf_hw(fmaxf(c[2], 0.f) * bf2f(a.z))
                | ((unsigned)f2bf_hw(fmaxf(c[3], 0.f) * bf2f(a.w)) << 16);
            *(uint2*)(saw + ln * 40 + mt * 16 + kb * 4) = q;
        }
    };

    auto conv = [&](int buf) {
        // A-frag: wave-private s_a, row n=ln, k(m)=kb*8+j (in-wave ordering)
        short8 af = *(const short8*)(saw + ln * 40 + kb * 8);
#pragma unroll
        for (int fb = 0; fb < 4; ++fb) {
            const int frow = fh * 64 + fb * 16 + ln;
            short8 bfrag = *(const short8*)(
                &s_sup[buf][frow * 32 + ((kb) ^ ((frow >> 1) & 3)) * 8]);
            acc[fb] = __builtin_amdgcn_mfma_f32_16x16x32_bf16(af, bfrag, acc[fb], 0, 0, 0);
        }
    };

    // r9-proven drain barrier: staged writes landed + all LDS ops done.
    auto bar_vm0 = []() {
        asm volatile("s_waitcnt vmcnt(0) lgkmcnt(0)" ::: "memory");
        __builtin_amdgcn_s_barrier();
    };

    ushort4 avA[2], avB[2];

    // prologue: chunk 0
    stage(0, 0);
    loadAdj(0, avA);
    bar_vm0();

    for (int tt = 0; tt < 32; tt += 2) {
        // ---- chunk tt (buf0): issue tt+1 staging first, hide under compute
        stage(1, (tt + 1) * 32);
        loadAdj((tt + 1) * 32, avB);
        score(0, avA);
        conv(0);
        bar_vm0();      // tile tt+1 ready; buf0 reads done

        // ---- chunk tt+1 (buf1)
        if (tt + 2 < 32) {
            stage(0, (tt + 2) * 32);
            loadAdj((tt + 2) * 32, avA);
        }
        score(1, avB);
        conv(1);
        bar_vm0();
    }

    // epilogue: out = relu(conv + bias + residual)
#pragma unroll
    for (int fb = 0; fb < 4; ++fb) {
        const int f = fh * 64 + fb * 16 + ln;
        const float bi = bias[f];
#pragma unroll
        for (int ii = 0; ii < 4; ++ii) {
            const int n = n0 + ns * 16 + kb * 4 + ii;      // <= 1023
            const size_t o = ((size_t)b * N_ + n) * F_ + f;
            out[o] = fmaxf(acc[fb][ii] + bi + bf2f(resid[o]), 0.f);
        }
    }
}

// ---------------------------------------------------------------------------
extern "C" void kernel_launch(void* const* d_in, const int* in_sizes, int n_in,
                              void* d_out, int out_size, void* d_ws, size_t ws_size,
                              hipStream_t stream) {
    const float* input_features = (const float*)d_in[0];
    const int*   cycle_indices  = (const int*)  d_in[1];
    const float* weight         = (const float*)d_in[2];
    const float* bias           = (const float*)d_in[3];
    const float* src_emb        = (const float*)d_in[4];
    const float* tgt_emb        = (const float*)d_in[5];
    const float* env_W          = (const float*)d_in[6];
    const float* env_b          = (const float*)d_in[7];
    const float* res_W          = (const float*)d_in[8];
    const float* res_b          = (const float*)d_in[9];
    const float* static_adj     = (const float*)d_in[10];
    const float* env_features   = (const float*)d_in[11];
    float* out = (float*)d_out;

    // workspace layout (~25.2 MiB)
    char* wsb = (char*)d_ws;
    unsigned short* src_bf = (unsigned short*)wsb;               // 3145728 B
    unsigned short* tgt_bf = src_bf + (size_t)NPER * N_ * H_;    // 3145728 B
    unsigned short* Wt     = tgt_bf + (size_t)NPER * N_ * H_;    // 32768 B
    unsigned short* rWt    = Wt + 16384;                         // 32768 B
    unsigned short* supT   = rWt + 16384;                        // 8388608 B
    unsigned short* resid  = supT + (size_t)B_ * F_ * N_;        // 8388608 B
    unsigned short* adj_bf = resid + (size_t)B_ * N_ * F_;       // 2097152 B

    prep_all<<<1408, 256, 0, stream>>>(
        src_emb, tgt_emb, env_features, env_W, env_b,
        static_adj, weight, res_W,
        src_bf, tgt_bf, adj_bf, Wt, rWt);

    gemm2_mfma<<<(B_ * N_) / 32, 256, 0, stream>>>(
        input_features, Wt, rWt, res_b, supT, resid);

    conv_mfma<<<1024, 256, 0, stream>>>(
        src_bf, tgt_bf, adj_bf, supT, resid, bias, cycle_indices, out);
}

// Round 15
// 71.231 us; speedup vs baseline: 1.1420x; 1.1420x over previous
//
#include <hip/hip_runtime.h>
#include <hip/hip_bf16.h>

#define NPER 24
#define B_ 32
#define N_ 1024
#define F_ 128
#define H_ 64
#define E_ 16

typedef __attribute__((ext_vector_type(8))) short short8;
typedef __attribute__((ext_vector_type(4))) float f32x4;

#define GLD16(g, l) __builtin_amdgcn_global_load_lds( \
    (const __attribute__((address_space(1))) void*)(g), \
    (__attribute__((address_space(3))) void*)(l), 16, 0, 0)

static __device__ __forceinline__ unsigned short f2bf(float x) {
    union { float f; unsigned u; } v; v.f = x;
    unsigned r = v.u + 0x7fffu + ((v.u >> 16) & 1u);   // RNE
    return (unsigned short)(r >> 16);
}
static __device__ __forceinline__ float bf2f(unsigned short h) {
    union { unsigned u; float f; } v; v.u = ((unsigned)h) << 16; return v.f;
}
static __device__ __forceinline__ unsigned short f2bf_hw(float x) {
    __hip_bfloat16 h = __float2bfloat16(x);
    return *(unsigned short*)&h;
}

// ---------------------------------------------------------------------------
// P1: all prep in one launch; srctgt TLP 6x (p-groups of 4).
//   blocks [0,1536):    src/tgt bf16, block g=bid/256 covers periods [4g,4g+4)
//   blocks [1536,2560): adj -> bf16
//   blocks [2560,2688): W / res_W transpose -> bf16
// ---------------------------------------------------------------------------
__global__ __launch_bounds__(256) void prep_all(
    const float* __restrict__ src_emb, const float* __restrict__ tgt_emb,
    const float* __restrict__ env_features, const float* __restrict__ env_W,
    const float* __restrict__ env_b,
    const float* __restrict__ adj, const float* __restrict__ W,
    const float* __restrict__ rW,
    unsigned short* __restrict__ src_bf, unsigned short* __restrict__ tgt_bf,
    unsigned short* __restrict__ adj_bf, unsigned short* __restrict__ Wt,
    unsigned short* __restrict__ rWt)
{
    const int bid = blockIdx.x;
    if (bid < 1536) {
        const int g   = bid >> 8;                    // p-group 0..5
        const int idx = (bid & 255) * 256 + threadIdx.x;   // 0..65535
        const int n = idx >> 6, h = idx & 63;
        float e = env_b[h];
#pragma unroll
        for (int k = 0; k < E_; ++k)
            e = fmaf(env_features[n * E_ + k], env_W[k * H_ + h], e);
        e = fmaxf(e, 0.f);
#pragma unroll
        for (int pp = 0; pp < 4; ++pp) {
            const size_t off = (size_t)(g * 4 + pp) * (N_ * H_) + idx;
            src_bf[off] = f2bf(src_emb[off] + e);
            tgt_bf[off] = f2bf(tgt_emb[off] + e);
        }
    } else if (bid < 2560) {
        const size_t i = ((size_t)(bid - 1536) * 256 + threadIdx.x) * 4;
        float4 v = *(const float4*)(adj + i);
        ushort4 o;
        o.x = f2bf(v.x); o.y = f2bf(v.y); o.z = f2bf(v.z); o.w = f2bf(v.w);
        *(ushort4*)(adj_bf + i) = o;
    } else {
        const int idx = (bid - 2560) * 256 + threadIdx.x;   // 0..32767
        const int which = idx >> 14, j = idx & 16383;
        const int f = j >> 7, d = j & 127;
        if (which == 0) Wt[f * 128 + d]  = f2bf(W[d * 128 + f]);
        else            rWt[f * 128 + d] = f2bf(rW[d * 128 + f]);
    }
}

// ---------------------------------------------------------------------------
// K5: support^T (swapped GEMM) + residual, both bf16 out, MFMA. [unchanged]
// ---------------------------------------------------------------------------
__global__ __launch_bounds__(256) void gemm2_mfma(
    const float* __restrict__ x,               // [B*N][128] fp32
    const unsigned short* __restrict__ Wt,     // [128f][128d]
    const unsigned short* __restrict__ rWt,    // [128f][128d]
    const float* __restrict__ rb,              // [128]
    unsigned short* __restrict__ supT,         // [B][128f][1024m]
    unsigned short* __restrict__ resid)        // [B*N][128]
{
    const int t = threadIdx.x, w = t >> 6, l = t & 63;
    const int ln = l & 15, kb = l >> 4;
    const int mblk = w >> 1, fhalf = w & 1;
    const int row0 = blockIdx.x * 32;
    const int b   = row0 >> 10;
    const int mg0 = row0 & 1023;

    const float* xrow = x + (size_t)(row0 + mblk * 16 + ln) * 128;
    short8 xa[4];
#pragma unroll
    for (int k = 0; k < 4; ++k) {
        float4 v0 = *(const float4*)(xrow + k * 32 + kb * 8);
        float4 v1 = *(const float4*)(xrow + k * 32 + kb * 8 + 4);
        short8 s;
        s[0] = (short)f2bf(v0.x); s[1] = (short)f2bf(v0.y);
        s[2] = (short)f2bf(v0.z); s[3] = (short)f2bf(v0.w);
        s[4] = (short)f2bf(v1.x); s[5] = (short)f2bf(v1.y);
        s[6] = (short)f2bf(v1.z); s[7] = (short)f2bf(v1.w);
        xa[k] = s;
    }

    f32x4 accS[4], accR[4];
#pragma unroll
    for (int i = 0; i < 4; ++i) { accS[i] = (f32x4){0,0,0,0}; accR[i] = (f32x4){0,0,0,0}; }

#pragma unroll
    for (int k = 0; k < 4; ++k) {
#pragma unroll
        for (int fb = 0; fb < 4; ++fb) {
            int fr = (fhalf * 4 + fb) * 16 + ln;
            short8 wa = *(const short8*)(Wt  + (size_t)fr * 128 + k * 32 + kb * 8);
            short8 wb = *(const short8*)(rWt + (size_t)fr * 128 + k * 32 + kb * 8);
            accS[fb] = __builtin_amdgcn_mfma_f32_16x16x32_bf16(wa, xa[k], accS[fb], 0, 0, 0);
            accR[fb] = __builtin_amdgcn_mfma_f32_16x16x32_bf16(xa[k], wb, accR[fb], 0, 0, 0);
        }
    }

#pragma unroll
    for (int fb = 0; fb < 4; ++fb) {
        int m = mg0 + mblk * 16 + ln;
#pragma unroll
        for (int i = 0; i < 4; ++i) {
            int f = (fhalf * 4 + fb) * 16 + kb * 4 + i;
            supT[((size_t)b * 128 + f) * 1024 + m] = f2bf(accS[fb][i]);
        }
    }
#pragma unroll
    for (int fb = 0; fb < 4; ++fb) {
        int f = (fhalf * 4 + fb) * 16 + ln;
        float rbf = rb[f];
#pragma unroll
        for (int i = 0; i < 4; ++i) {
            size_t row = (size_t)row0 + mblk * 16 + kb * 4 + i;
            resid[row * 128 + f] = f2bf(fmaxf(accR[fb][i] + rbf, 0.f));
        }
    }
}

// ---------------------------------------------------------------------------
// K6: r9 shell + IN-WAVE phase handoff (r8 ablation: phases were additive
// because of the cross-wave s_a barrier; make them overlappable).
// Block = (b, 64-row n-tile), grid 512 XCD-swizzled, 4 waves, 2 blocks/CU
// (57 KB LDS). Wave w owns n-strip [n0+w*16,+16) END-TO-END:
//   score: its 16n x 64m (8 MFMA) -> wave-private s_a[16][72]
//   conv:  its 16n x 128f, K=64m (16 MFMA), af from private s_a
// No barrier between phases (same-wave DS ordering); ONE bar_vm0 per chunk
// (tile readiness + buf reuse, r9-proven). Staging identical to r9: tgt 8KB
// + sup 16KB per 64-m chunk via global_load_lds, both-sides swizzle c^(r&7)
// (128B rows both). No score duplication (r14's mistake).
// ---------------------------------------------------------------------------
__global__ __launch_bounds__(256, 2) void conv_mfma(
    const unsigned short* __restrict__ src_bf,  // [P][N][64]
    const unsigned short* __restrict__ tgt_bf,  // [P][N][64]
    const unsigned short* __restrict__ adj_bf,  // [N][N]
    const unsigned short* __restrict__ supT,    // [B][128][1024]
    const unsigned short* __restrict__ resid,   // [B*N][128]
    const float* __restrict__ bias,             // [128]
    const int* __restrict__ cyc,                // [B]
    float* __restrict__ out)                    // [B][N][128]
{
    __shared__ unsigned short s_tgt[2][64 * 64] __attribute__((aligned(16)));   // 2x8KB
    __shared__ unsigned short s_sup[2][128 * 64] __attribute__((aligned(16)));  // 2x16KB
    __shared__ unsigned short s_a[4][16 * 72] __attribute__((aligned(16)));     // 9KB

    const int i = blockIdx.x;                    // 0..511
    const int work = (i & 7) * 64 + (i >> 3);    // XCD k: 2 consecutive b's
    const int b  = work >> 4;
    const int n0 = (work & 15) * 64;

    const int t = threadIdx.x, w = t >> 6, l = t & 63;
    const int ln = l & 15, kb = l >> 4;
    const int p = ((cyc[b] % NPER) + NPER) % NPER;

    // wave-private n-strip rows: n0 + w*16 + (0..15)   (w*16+15 <= 63, in-block)
    const unsigned short* srow =
        src_bf + ((size_t)p * N_ + n0 + w * 16 + ln) * H_;
    short8 sfrag[2];
    sfrag[0] = *(const short8*)(srow + kb * 8);
    sfrag[1] = *(const short8*)(srow + 32 + kb * 8);

    const unsigned short* tgtg = tgt_bf + (size_t)p * N_ * H_;
    const unsigned short* supg = supT + (size_t)b * F_ * N_;
    const unsigned short* adjp = adj_bf + (size_t)(n0 + w * 16 + ln) * N_;
    unsigned short* saw = &s_a[w][0];

    f32x4 acc[8];    // 16n x 128f per wave
#pragma unroll
    for (int q = 0; q < 8; ++q) acc[q] = (f32x4){0, 0, 0, 0};

    auto stage = [&](int buf, int m0) {
        // tgt: 64 m-rows x 8 chunks(16B), src-side swizzle c^(r&7)
#pragma unroll
        for (int j = 0; j < 2; ++j) {
            const int te = j * 256 + t;
            const int r = te >> 3, c = te & 7;
            GLD16(tgtg + (size_t)(m0 + r) * H_ + (c ^ (r & 7)) * 8,
                  &s_tgt[buf][te * 8]);
        }
        // sup: 128 f-rows x 8 chunks(16B), swizzle c^(r&7)
#pragma unroll
        for (int j = 0; j < 4; ++j) {
            const int te = j * 256 + t;
            const int r = te >> 3, c = te & 7;
            GLD16(supg + (size_t)r * N_ + m0 + (c ^ (r & 7)) * 8,
                  &s_sup[buf][te * 8]);
        }
    };

    auto loadAdj = [&](int m0, ushort4 (&av)[4]) {
#pragma unroll
        for (int mt = 0; mt < 4; ++mt)
            av[mt] = *(const ushort4*)(adjp + m0 + mt * 16 + kb * 4);
    };

    auto score = [&](int buf, const ushort4 (&av)[4]) {
#pragma unroll
        for (int mt = 0; mt < 4; ++mt) {
            const int trow = mt * 16 + ln;     // m-row within chunk
            short8 tf0 = *(const short8*)(
                &s_tgt[buf][trow * 64 + ((kb) ^ (trow & 7)) * 8]);
            short8 tf1 = *(const short8*)(
                &s_tgt[buf][trow * 64 + ((4 + kb) ^ (trow & 7)) * 8]);
            f32x4 c = (f32x4){0, 0, 0, 0};
            c = __builtin_amdgcn_mfma_f32_16x16x32_bf16(tf0, sfrag[0], c, 0, 0, 0);
            c = __builtin_amdgcn_mfma_f32_16x16x32_bf16(tf1, sfrag[1], c, 0, 0, 0);
            // lane holds score[m = mt*16+kb*4+i][n = ln]  (r9-verified layout)
            const ushort4 a = av[mt];
            uint2 q;
            q.x = (unsigned)f2bf_hw(fmaxf(c[0], 0.f) * bf2f(a.x))
                | ((unsigned)f2bf_hw(fmaxf(c[1], 0.f) * bf2f(a.y)) << 16);
            q.y = (unsigned)f2bf_hw(fmaxf(c[2], 0.f) * bf2f(a.z))
                | ((unsigned)f2bf_hw(fmaxf(c[3], 0.f) * bf2f(a.w)) << 16);
            *(uint2*)(saw + ln * 72 + mt * 16 + kb * 4) = q;
        }
    };

    auto conv = [&](int buf) {
#pragma unroll
        for (int ks = 0; ks < 2; ++ks) {
            // A-frag: wave-private s_a, row n = ln, k(m) = ks*32 + kb*8 + j
            short8 af = *(const short8*)(saw + ln * 72 + ks * 32 + kb * 8);
#pragma unroll
            for (int fb = 0; fb < 8; ++fb) {
                const int frow = fb * 16 + ln;
                short8 bfrag = *(const short8*)(
                    &s_sup[buf][frow * 64 + ((ks * 4 + kb) ^ (frow & 7)) * 8]);
                acc[fb] = __builtin_amdgcn_mfma_f32_16x16x32_bf16(
                    af, bfrag, acc[fb], 0, 0, 0);
            }
        }
    };

    // r9-proven drain barrier: staged writes landed + all LDS ops done.
    auto bar_vm0 = []() {
        asm volatile("s_waitcnt vmcnt(0) lgkmcnt(0)" ::: "memory");
        __builtin_amdgcn_s_barrier();
    };

    ushort4 avA[4], avB[4];

    // prologue: chunk 0
    stage(0, 0);
    loadAdj(0, avA);
    bar_vm0();

    for (int tt = 0; tt < 16; tt += 2) {
        // ---- chunk tt (buf0): issue tt+1 staging first, hide under compute
        stage(1, (tt + 1) * 64);
        loadAdj((tt + 1) * 64, avB);
        score(0, avA);
        conv(0);        // in-wave handoff; compiler interleaves with score
        bar_vm0();      // tile tt+1 ready; buf0 reads done

        // ---- chunk tt+1 (buf1)
        if (tt + 2 < 16) {
            stage(0, (tt + 2) * 64);
            loadAdj((tt + 2) * 64, avA);
        }
        score(1, avB);
        conv(1);
        bar_vm0();
    }

    // epilogue: out = relu(conv + bias + residual)
#pragma unroll
    for (int fb = 0; fb < 8; ++fb) {
        const int f = fb * 16 + ln;
        const float bi = bias[f];
#pragma unroll
        for (int ii = 0; ii < 4; ++ii) {
            const int n = n0 + w * 16 + kb * 4 + ii;       // <= n0+63
            const size_t o = ((size_t)b * N_ + n) * F_ + f;
            out[o] = fmaxf(acc[fb][ii] + bi + bf2f(resid[o]), 0.f);
        }
    }
}

// ---------------------------------------------------------------------------
extern "C" void kernel_launch(void* const* d_in, const int* in_sizes, int n_in,
                              void* d_out, int out_size, void* d_ws, size_t ws_size,
                              hipStream_t stream) {
    const float* input_features = (const float*)d_in[0];
    const int*   cycle_indices  = (const int*)  d_in[1];
    const float* weight         = (const float*)d_in[2];
    const float* bias           = (const float*)d_in[3];
    const float* src_emb        = (const float*)d_in[4];
    const float* tgt_emb        = (const float*)d_in[5];
    const float* env_W          = (const float*)d_in[6];
    const float* env_b          = (const float*)d_in[7];
    const float* res_W          = (const float*)d_in[8];
    const float* res_b          = (const float*)d_in[9];
    const float* static_adj     = (const float*)d_in[10];
    const float* env_features   = (const float*)d_in[11];
    float* out = (float*)d_out;

    // workspace layout (~25.2 MiB)
    char* wsb = (char*)d_ws;
    unsigned short* src_bf = (unsigned short*)wsb;               // 3145728 B
    unsigned short* tgt_bf = src_bf + (size_t)NPER * N_ * H_;    // 3145728 B
    unsigned short* Wt     = tgt_bf + (size_t)NPER * N_ * H_;    // 32768 B
    unsigned short* rWt    = Wt + 16384;                         // 32768 B
    unsigned short* supT   = rWt + 16384;                        // 8388608 B
    unsigned short* resid  = supT + (size_t)B_ * F_ * N_;        // 8388608 B
    unsigned short* adj_bf = resid + (size_t)B_ * N_ * F_;       // 2097152 B

    prep_all<<<2688, 256, 0, stream>>>(
        src_emb, tgt_emb, env_features, env_W, env_b,
        static_adj, weight, res_W,
        src_bf, tgt_bf, adj_bf, Wt, rWt);

    gemm2_mfma<<<(B_ * N_) / 32, 256, 0, stream>>>(
        input_features, Wt, rWt, res_b, supT, resid);

    conv_mfma<<<512, 256, 0, stream>>>(
        src_bf, tgt_bf, adj_bf, supT, resid, bias, cycle_indices, out);
}